// Round 1
// baseline (1152.576 us; speedup 1.0000x reference)
//
#include <hip/hip_runtime.h>

#define N_PIX 9216
#define CCH 256
#define W_ 96
#define H_ 96
#define BM 128
#define BN 128
#define BK 16
#define TM 8
#define TN 8

// Monotone encoding: unsigned compare order == float compare order.
__device__ __forceinline__ unsigned int mono_enc(float f) {
    unsigned int u = __float_as_uint(f);
    return (u & 0x80000000u) ? ~u : (u | 0x80000000u);
}
__device__ __forceinline__ float mono_dec(unsigned int e) {
    return __uint_as_float((e & 0x80000000u) ? (e ^ 0x80000000u) : ~e);
}

__global__ __launch_bounds__(256) void norms_kernel(const float* __restrict__ Q,
                                                    const float* __restrict__ P,
                                                    float* __restrict__ invq,
                                                    float* __restrict__ invp) {
    int n = blockIdx.x * blockDim.x + threadIdx.x;
    if (n >= N_PIX) return;
    float sq = 0.f, sp = 0.f;
    for (int c = 0; c < CCH; ++c) {
        float a = Q[(size_t)c * N_PIX + n];
        float b = P[(size_t)c * N_PIX + n];
        sq = fmaf(a, a, sq);
        sp = fmaf(b, b, sp);
    }
    invq[n] = 1.0f / sqrtf(sq);
    invp[n] = 1.0f / sqrtf(sp);
}

__global__ __launch_bounds__(256) void gemm_kernel(const float* __restrict__ Q,
                                                   const float* __restrict__ P,
                                                   const float* __restrict__ invq,
                                                   const float* __restrict__ invp,
                                                   float* __restrict__ sim,
                                                   unsigned long long* __restrict__ row_best,
                                                   unsigned long long* __restrict__ col_best) {
    __shared__ union SH {
        struct { float A[BK][BM]; float B[BK][BN]; } t;   // 16 KB
        unsigned long long red[16][128];                  // 16 KB (reused after K-loop)
    } sh;

    const int tid = threadIdx.x;
    const int tx = tid & 15;   // 0..15  (col group)
    const int ty = tid >> 4;   // 0..15  (row group)
    const int n0 = blockIdx.y * BM;  // query rows
    const int m0 = blockIdx.x * BN;  // projection cols

    float acc[TM][TN];
#pragma unroll
    for (int i = 0; i < TM; ++i)
#pragma unroll
        for (int j = 0; j < TN; ++j) acc[i][j] = 0.f;

    for (int kk = 0; kk < CCH; kk += BK) {
#pragma unroll
        for (int rep = 0; rep < 2; ++rep) {
            int idx = tid + rep * 256;       // float4 id, 0..511
            int row = idx >> 5;              // 0..15 (k within tile)
            int c4  = idx & 31;              // 0..31 (float4 within 128)
            float4 av = *(const float4*)&Q[(size_t)(kk + row) * N_PIX + n0 + c4 * 4];
            float4 bv = *(const float4*)&P[(size_t)(kk + row) * N_PIX + m0 + c4 * 4];
            *(float4*)&sh.t.A[row][c4 * 4] = av;
            *(float4*)&sh.t.B[row][c4 * 4] = bv;
        }
        __syncthreads();
#pragma unroll
        for (int k = 0; k < BK; ++k) {
            float a[TM], b[TN];
            *(float4*)&a[0] = *(const float4*)&sh.t.A[k][ty * TM];
            *(float4*)&a[4] = *(const float4*)&sh.t.A[k][ty * TM + 4];
            *(float4*)&b[0] = *(const float4*)&sh.t.B[k][tx * TN];
            *(float4*)&b[4] = *(const float4*)&sh.t.B[k][tx * TN + 4];
#pragma unroll
            for (int i = 0; i < TM; ++i)
#pragma unroll
                for (int j = 0; j < TN; ++j)
                    acc[i][j] = fmaf(a[i], b[j], acc[i][j]);
        }
        __syncthreads();
    }

    // scale by inverse norms (same value that gets stored is used for argmax)
    float iq[TM], ip[TN];
#pragma unroll
    for (int i = 0; i < TM; ++i) iq[i] = invq[n0 + ty * TM + i];
#pragma unroll
    for (int j = 0; j < TN; ++j) ip[j] = invp[m0 + tx * TN + j];
#pragma unroll
    for (int i = 0; i < TM; ++i)
#pragma unroll
        for (int j = 0; j < TN; ++j) acc[i][j] *= iq[i] * ip[j];

    // store sim tile
#pragma unroll
    for (int i = 0; i < TM; ++i) {
        int n = n0 + ty * TM + i;
        float4 v0 = make_float4(acc[i][0], acc[i][1], acc[i][2], acc[i][3]);
        float4 v1 = make_float4(acc[i][4], acc[i][5], acc[i][6], acc[i][7]);
        float* dst = &sim[(size_t)n * N_PIX + m0 + tx * TN];
        *(float4*)dst = v0;
        *(float4*)(dst + 4) = v1;
    }

    // ---- row bests: for each row n in tile, max over this tile's 128 cols ----
    // (tiles in LDS are dead after final __syncthreads in K-loop)
#pragma unroll
    for (int i = 0; i < TM; ++i) {
        float best = acc[i][0]; int bj = 0;
#pragma unroll
        for (int j = 1; j < TN; ++j)
            if (acc[i][j] > best) { best = acc[i][j]; bj = j; }
        unsigned int gcol = (unsigned int)(m0 + tx * TN + bj);
        sh.red[tx][ty * TM + i] =
            ((unsigned long long)mono_enc(best) << 32) | (unsigned long long)(0xFFFFFFFFu - gcol);
    }
    __syncthreads();
    if (tid < 128) {
        unsigned long long best = sh.red[0][tid];
#pragma unroll
        for (int x = 1; x < 16; ++x) {
            unsigned long long v = sh.red[x][tid];
            if (v > best) best = v;
        }
        atomicMax(&row_best[n0 + tid], best);
    }
    __syncthreads();

    // ---- col bests: for each col m in tile, max over this tile's 128 rows ----
#pragma unroll
    for (int j = 0; j < TN; ++j) {
        float best = acc[0][j]; int bi = 0;
#pragma unroll
        for (int i = 1; i < TM; ++i)
            if (acc[i][j] > best) { best = acc[i][j]; bi = i; }
        unsigned int grow = (unsigned int)(n0 + ty * TM + bi);
        sh.red[ty][tx * TN + j] =
            ((unsigned long long)mono_enc(best) << 32) | (unsigned long long)(0xFFFFFFFFu - grow);
    }
    __syncthreads();
    if (tid < 128) {
        unsigned long long best = sh.red[0][tid];
#pragma unroll
        for (int x = 1; x < 16; ++x) {
            unsigned long long v = sh.red[x][tid];
            if (v > best) best = v;
        }
        atomicMax(&col_best[m0 + tid], best);
    }
}

__global__ __launch_bounds__(256) void epilogue_kernel(const unsigned long long* __restrict__ row_best,
                                                       const unsigned long long* __restrict__ col_best,
                                                       float* __restrict__ out) {
    int j = blockIdx.x * blockDim.x + threadIdx.x;
    if (j >= N_PIX) return;
    unsigned long long cb = col_best[j];
    unsigned int q_idx = 0xFFFFFFFFu - (unsigned int)(cb & 0xFFFFFFFFull);
    float simval = mono_dec((unsigned int)(cb >> 32));
    unsigned long long rb = row_best[q_idx];
    unsigned int rm = 0xFFFFFFFFu - (unsigned int)(rb & 0xFFFFFFFFull);
    bool mutual = (rm == (unsigned int)j) && (simval > 0.9f);
    int qd = (int)(q_idx / W_), qm = (int)(q_idx % W_);
    int pd = j / W_, pm = j % W_;
    bool valid = mutual && (qd + 1 < H_) && (pd + 1 < H_);
    size_t base = (size_t)N_PIX * N_PIX;
    out[base + 0 * (size_t)N_PIX + j] = valid ? 1.0f : 0.0f;
    out[base + 1 * (size_t)N_PIX + j] = (float)q_idx;
    out[base + 2 * (size_t)N_PIX + j] = (float)qd;
    out[base + 3 * (size_t)N_PIX + j] = (float)qm;
    out[base + 4 * (size_t)N_PIX + j] = (float)pd;
    out[base + 5 * (size_t)N_PIX + j] = (float)pm;
}

extern "C" void kernel_launch(void* const* d_in, const int* in_sizes, int n_in,
                              void* d_out, int out_size, void* d_ws, size_t ws_size,
                              hipStream_t stream) {
    const float* Q = (const float*)d_in[0];
    const float* P = (const float*)d_in[1];
    float* out = (float*)d_out;

    unsigned long long* row_best = (unsigned long long*)d_ws;
    unsigned long long* col_best = row_best + N_PIX;
    float* invq = (float*)(col_best + N_PIX);
    float* invp = invq + N_PIX;

    // init packed argmax slots to 0 (== -inf under monotone encoding)
    hipMemsetAsync(d_ws, 0, 2 * N_PIX * sizeof(unsigned long long), stream);

    norms_kernel<<<N_PIX / 256, 256, 0, stream>>>(Q, P, invq, invp);

    dim3 grid(N_PIX / BN, N_PIX / BM);
    gemm_kernel<<<grid, 256, 0, stream>>>(Q, P, invq, invp, out, row_best, col_best);

    epilogue_kernel<<<N_PIX / 256, 256, 0, stream>>>(row_best, col_best, out);
}

// Round 2
// 941.572 us; speedup vs baseline: 1.2241x; 1.2241x over previous
//
#include <hip/hip_runtime.h>

#define N_PIX 9216
#define CCH 256
#define W_ 96
#define H_ 96
#define BM 128
#define BN 128
#define BK 16
#define TM 8
#define TN 8

// Monotone encoding: unsigned compare order == float compare order.
__device__ __forceinline__ unsigned int mono_enc(float f) {
    unsigned int u = __float_as_uint(f);
    return (u & 0x80000000u) ? ~u : (u | 0x80000000u);
}
__device__ __forceinline__ float mono_dec(unsigned int e) {
    return __uint_as_float((e & 0x80000000u) ? (e ^ 0x80000000u) : ~e);
}

__global__ __launch_bounds__(256) void norms_kernel(const float* __restrict__ Q,
                                                    const float* __restrict__ P,
                                                    float* __restrict__ invq,
                                                    float* __restrict__ invp) {
    int n = blockIdx.x * blockDim.x + threadIdx.x;
    if (n >= N_PIX) return;
    float sq = 0.f, sp = 0.f;
    for (int c = 0; c < CCH; ++c) {
        float a = Q[(size_t)c * N_PIX + n];
        float b = P[(size_t)c * N_PIX + n];
        sq = fmaf(a, a, sq);
        sp = fmaf(b, b, sp);
    }
    invq[n] = 1.0f / sqrtf(sq);
    invp[n] = 1.0f / sqrtf(sp);
}

// Split micro-tile: thread (tx,ty) owns cols {tx*4+0..3, 64+tx*4+0..3},
// rows {ty*4+0..3, 64+ty*4+0..3}. LDS fragment reads are then lane-stride
// 16B -> banks tx*4%32 -> only 2-way aliasing (free), vs 4-way for the
// adjacent-8 layout (2.8e8 conflict cycles in round 1).
__device__ __forceinline__ int local_row(int ty, int i) {
    return (i < 4) ? (ty * 4 + i) : (64 + ty * 4 + (i - 4));
}
__device__ __forceinline__ int local_col(int tx, int j) {
    return (j < 4) ? (tx * 4 + j) : (64 + tx * 4 + (j - 4));
}

__global__ __launch_bounds__(256) void gemm_kernel(const float* __restrict__ Q,
                                                   const float* __restrict__ P,
                                                   const float* __restrict__ invq,
                                                   const float* __restrict__ invp,
                                                   float* __restrict__ sim,
                                                   unsigned long long* __restrict__ row_best,
                                                   unsigned long long* __restrict__ col_best) {
    __shared__ union SH {
        struct { float A[BK][BM]; float B[BK][BN]; } t;   // 16 KB
        unsigned long long red[16][128];                  // 16 KB (reused after K-loop)
    } sh;

    const int tid = threadIdx.x;
    const int tx = tid & 15;   // 0..15  (col group)
    const int ty = tid >> 4;   // 0..15  (row group)
    const int n0 = blockIdx.y * BM;  // query rows
    const int m0 = blockIdx.x * BN;  // projection cols

    float acc[TM][TN];
#pragma unroll
    for (int i = 0; i < TM; ++i)
#pragma unroll
        for (int j = 0; j < TN; ++j) acc[i][j] = 0.f;

    for (int kk = 0; kk < CCH; kk += BK) {
#pragma unroll
        for (int rep = 0; rep < 2; ++rep) {
            int idx = tid + rep * 256;       // float4 id, 0..511
            int row = idx >> 5;              // 0..15 (k within tile)
            int c4  = idx & 31;              // 0..31 (float4 within 128)
            float4 av = *(const float4*)&Q[(size_t)(kk + row) * N_PIX + n0 + c4 * 4];
            float4 bv = *(const float4*)&P[(size_t)(kk + row) * N_PIX + m0 + c4 * 4];
            *(float4*)&sh.t.A[row][c4 * 4] = av;
            *(float4*)&sh.t.B[row][c4 * 4] = bv;
        }
        __syncthreads();
#pragma unroll
        for (int k = 0; k < BK; ++k) {
            float a[TM], b[TN];
            *(float4*)&a[0] = *(const float4*)&sh.t.A[k][ty * 4];
            *(float4*)&a[4] = *(const float4*)&sh.t.A[k][ty * 4 + 64];
            *(float4*)&b[0] = *(const float4*)&sh.t.B[k][tx * 4];
            *(float4*)&b[4] = *(const float4*)&sh.t.B[k][tx * 4 + 64];
#pragma unroll
            for (int i = 0; i < TM; ++i)
#pragma unroll
                for (int j = 0; j < TN; ++j)
                    acc[i][j] = fmaf(a[i], b[j], acc[i][j]);
        }
        __syncthreads();
    }

    // scale by inverse norms (same value that gets stored is used for argmax)
    float iq[TM], ip[TN];
#pragma unroll
    for (int i = 0; i < TM; ++i) iq[i] = invq[n0 + local_row(ty, i)];
#pragma unroll
    for (int j = 0; j < TN; ++j) ip[j] = invp[m0 + local_col(tx, j)];
#pragma unroll
    for (int i = 0; i < TM; ++i)
#pragma unroll
        for (int j = 0; j < TN; ++j) acc[i][j] *= iq[i] * ip[j];

    // store sim tile: two float4 runs per row (cols tx*4 and 64+tx*4)
#pragma unroll
    for (int i = 0; i < TM; ++i) {
        int n = n0 + local_row(ty, i);
        float4 v0 = make_float4(acc[i][0], acc[i][1], acc[i][2], acc[i][3]);
        float4 v1 = make_float4(acc[i][4], acc[i][5], acc[i][6], acc[i][7]);
        float* dst = &sim[(size_t)n * N_PIX + m0];
        *(float4*)(dst + tx * 4) = v0;
        *(float4*)(dst + 64 + tx * 4) = v1;
    }

    // ---- row bests: for each local row r, max over this tile's 128 cols ----
#pragma unroll
    for (int i = 0; i < TM; ++i) {
        float best = acc[i][0]; int bj = 0;
#pragma unroll
        for (int j = 1; j < TN; ++j)
            if (acc[i][j] > best) { best = acc[i][j]; bj = j; }
        unsigned int gcol = (unsigned int)(m0 + local_col(tx, bj));
        sh.red[tx][local_row(ty, i)] =
            ((unsigned long long)mono_enc(best) << 32) | (unsigned long long)(0xFFFFFFFFu - gcol);
    }
    __syncthreads();
    if (tid < 128) {
        unsigned long long best = sh.red[0][tid];
#pragma unroll
        for (int x = 1; x < 16; ++x) {
            unsigned long long v = sh.red[x][tid];
            if (v > best) best = v;
        }
        atomicMax(&row_best[n0 + tid], best);
    }
    __syncthreads();

    // ---- col bests: for each local col c, max over this tile's 128 rows ----
#pragma unroll
    for (int j = 0; j < TN; ++j) {
        float best = acc[0][j]; int bi = 0;
#pragma unroll
        for (int i = 1; i < TM; ++i)
            if (acc[i][j] > best) { best = acc[i][j]; bi = i; }
        unsigned int grow = (unsigned int)(n0 + local_row(ty, bi));
        sh.red[ty][local_col(tx, j)] =
            ((unsigned long long)mono_enc(best) << 32) | (unsigned long long)(0xFFFFFFFFu - grow);
    }
    __syncthreads();
    if (tid < 128) {
        unsigned long long best = sh.red[0][tid];
#pragma unroll
        for (int x = 1; x < 16; ++x) {
            unsigned long long v = sh.red[x][tid];
            if (v > best) best = v;
        }
        atomicMax(&col_best[m0 + tid], best);
    }
}

__global__ __launch_bounds__(256) void epilogue_kernel(const unsigned long long* __restrict__ row_best,
                                                       const unsigned long long* __restrict__ col_best,
                                                       float* __restrict__ out) {
    int j = blockIdx.x * blockDim.x + threadIdx.x;
    if (j >= N_PIX) return;
    unsigned long long cb = col_best[j];
    unsigned int q_idx = 0xFFFFFFFFu - (unsigned int)(cb & 0xFFFFFFFFull);
    float simval = mono_dec((unsigned int)(cb >> 32));
    unsigned long long rb = row_best[q_idx];
    unsigned int rm = 0xFFFFFFFFu - (unsigned int)(rb & 0xFFFFFFFFull);
    bool mutual = (rm == (unsigned int)j) && (simval > 0.9f);
    int qd = (int)(q_idx / W_), qm = (int)(q_idx % W_);
    int pd = j / W_, pm = j % W_;
    bool valid = mutual && (qd + 1 < H_) && (pd + 1 < H_);
    size_t base = (size_t)N_PIX * N_PIX;
    out[base + 0 * (size_t)N_PIX + j] = valid ? 1.0f : 0.0f;
    out[base + 1 * (size_t)N_PIX + j] = (float)q_idx;
    out[base + 2 * (size_t)N_PIX + j] = (float)qd;
    out[base + 3 * (size_t)N_PIX + j] = (float)qm;
    out[base + 4 * (size_t)N_PIX + j] = (float)pd;
    out[base + 5 * (size_t)N_PIX + j] = (float)pm;
}

extern "C" void kernel_launch(void* const* d_in, const int* in_sizes, int n_in,
                              void* d_out, int out_size, void* d_ws, size_t ws_size,
                              hipStream_t stream) {
    const float* Q = (const float*)d_in[0];
    const float* P = (const float*)d_in[1];
    float* out = (float*)d_out;

    unsigned long long* row_best = (unsigned long long*)d_ws;
    unsigned long long* col_best = row_best + N_PIX;
    float* invq = (float*)(col_best + N_PIX);
    float* invp = invq + N_PIX;

    // init packed argmax slots to 0 (== -inf under monotone encoding)
    hipMemsetAsync(d_ws, 0, 2 * N_PIX * sizeof(unsigned long long), stream);

    norms_kernel<<<N_PIX / 256, 256, 0, stream>>>(Q, P, invq, invp);

    dim3 grid(N_PIX / BN, N_PIX / BM);
    gemm_kernel<<<grid, 256, 0, stream>>>(Q, P, invq, invp, out, row_best, col_best);

    epilogue_kernel<<<N_PIX / 256, 256, 0, stream>>>(row_best, col_best, out);
}